// Round 3
// baseline (3468.041 us; speedup 1.0000x reference)
//
#include <hip/hip_runtime.h>
#include <hip/hip_bf16.h>
#include <stdint.h>

#define NE 800000
#define NN 50000

// ---- workspace layout (float offsets) ----
#define O_W1   0          // We1  [129*64]
#define O_B1   8256       // be1  [64]
#define O_W2   8320       // We2  [64*64]
#define O_B2   12416      // be2  [64]
#define O_WC1  12480      // Wc1  [64*64]
#define O_BC1  16576      // bc1  [64]
#define O_WC2  16640      // Wc2  [64]
#define O_BC2  16704      // bc2  [1]
#define O_WN1  16768      // Wn1  [128*64]
#define O_BN1  24960      // bn1  [64]
#define O_WN2  25024      // Wn2  [64*64]
#define O_BN2  29120      // bn2  [64]
#define O_FLAG 29184      // int: 1 = tensors are bf16, 0 = tensors are f32
#define O_AGGH 29248                    // [NN*64] fp32 scatter-sum of edge_feat
#define O_SUMT (O_AGGH + NN*64)         // [NN*3]
#define O_CNT  (O_SUMT + NN*3)          // [NN]
#define WS_FLOATS (O_CNT + NN)

#define OUT_COORD (NN*64)
#define OUT_V     (NN*64 + NN*3)

static __device__ __forceinline__ float bf2f(const __hip_bfloat16 x) { return __bfloat162float(x); }

// generic element load: B16 ? bf16[i] : f32[i]
template<bool B16>
static __device__ __forceinline__ float ldf(const void* p, size_t i) {
    if (B16) return __bfloat162float(((const __hip_bfloat16*)p)[i]);
    else     return ((const float*)p)[i];
}
// generic element store: dtype of out follows dtype of inputs
template<bool B16>
static __device__ __forceinline__ void stf(void* p, size_t i, float v) {
    if (B16) ((__hip_bfloat16*)p)[i] = __float2bfloat16(v);
    else     ((float*)p)[i] = v;
}

// ---- dtype sniff: decide whether float tensors are bf16 or f32 ----
// We1 ~ U(-0.0884, 0.0884). Interpreted as bf16 pairs: bf16 mode -> all
// elements |x| <= 0.1; f32 mode -> low halves are mantissa garbage, ~50%
// violate per element (incl. NaN patterns). 128 dwords => P(wrong) ~ 1e-41.
__global__ void sniff_kernel(const uint32_t* __restrict__ w, float* __restrict__ ws) {
    int bad = 0;
    for (int i = 0; i < 128; ++i) {
        uint32_t d = w[i];
        float a = __uint_as_float(d << 16);
        float b = __uint_as_float(d & 0xffff0000u);
        if (!(fabsf(a) <= 0.1f)) bad++;   // NaN-safe: !(<=) catches NaN
        if (!(fabsf(b) <= 0.1f)) bad++;
    }
    ((int*)ws)[O_FLAG] = (bad == 0) ? 1 : 0;
}

// ---- weight -> fp32 conversion into ws (handles both modes) ----
__global__ void prep_kernel(
    const void* We1, const void* be1, const void* We2, const void* be2,
    const void* Wn1, const void* bn1, const void* Wn2, const void* bn2,
    const void* Wc1, const void* bc1, const void* Wc2, const void* bc2,
    float* __restrict__ wf)
{
    const int isb = ((const int*)wf)[O_FLAG];
    int tid = blockIdx.x * blockDim.x + threadIdx.x;
    int stride = gridDim.x * blockDim.x;
#define CP(dst, src, n) \
    for (int i = tid; i < (n); i += stride) \
        wf[(dst) + i] = isb ? bf2f(((const __hip_bfloat16*)(src))[i]) \
                            : ((const float*)(src))[i];
    CP(O_W1,  We1, 129*64)
    CP(O_B1,  be1, 64)
    CP(O_W2,  We2, 64*64)
    CP(O_B2,  be2, 64)
    CP(O_WC1, Wc1, 64*64)
    CP(O_BC1, bc1, 64)
    CP(O_WC2, Wc2, 64)
    CP(O_BC2, bc2, 1)
    CP(O_WN1, Wn1, 128*64)
    CP(O_BN1, bn1, 64)
    CP(O_WN2, Wn2, 64*64)
    CP(O_BN2, bn2, 64)
#undef CP
}

// ---- per-edge core: edge MLP + coord gate + atomic scatter ----
template<bool B16>
static __device__ __forceinline__ void edge_core(
    const void* __restrict__ h, const void* __restrict__ coord,
    const int* __restrict__ ei, float* __restrict__ ws, int e, float* my)
{
    const float* wf = ws;
    int row = ei[e];
    int col = ei[NE + e];

    float cdx = ldf<B16>(coord, 3*row + 0) - ldf<B16>(coord, 3*col + 0);
    float cdy = ldf<B16>(coord, 3*row + 1) - ldf<B16>(coord, 3*col + 1);
    float cdz = ldf<B16>(coord, 3*row + 2) - ldf<B16>(coord, 3*col + 2);
    float radial = cdx*cdx + cdy*cdy + cdz*cdz;

    float acc[64];
    #pragma unroll
    for (int j = 0; j < 64; ++j) acc[j] = wf[O_B1 + j];

    // layer 1: k = 0..63 (h[row])
    for (int k = 0; k < 64; ++k) {
        float a = ldf<B16>(h, (size_t)row * 64 + k);
        const float* w = wf + O_W1 + k * 64;
        #pragma unroll
        for (int j = 0; j < 64; ++j) acc[j] = fmaf(a, w[j], acc[j]);
    }
    // layer 1: k = 64..127 (h[col])
    for (int k = 0; k < 64; ++k) {
        float a = ldf<B16>(h, (size_t)col * 64 + k);
        const float* w = wf + O_W1 + (64 + k) * 64;
        #pragma unroll
        for (int j = 0; j < 64; ++j) acc[j] = fmaf(a, w[j], acc[j]);
    }
    // layer 1: k = 128 (radial)
    {
        const float* w = wf + O_W1 + 128 * 64;
        #pragma unroll
        for (int j = 0; j < 64; ++j) acc[j] = fmaf(radial, w[j], acc[j]);
    }

    // relu -> LDS (dynamic-k input of layer 2)
    #pragma unroll
    for (int j = 0; j < 64; ++j) my[j] = fmaxf(acc[j], 0.0f);

    // layer 2
    #pragma unroll
    for (int j = 0; j < 64; ++j) acc[j] = wf[O_B2 + j];
    for (int k = 0; k < 64; ++k) {
        float a = my[k];
        const float* w = wf + O_W2 + k * 64;
        #pragma unroll
        for (int j = 0; j < 64; ++j) acc[j] = fmaf(a, w[j], acc[j]);
    }
    // edge_feat = relu(...)
    #pragma unroll
    for (int j = 0; j < 64; ++j) acc[j] = fmaxf(acc[j], 0.0f);

    // scatter edge_feat into agg_h (fp32 atomics)
    {
        float* ah = ws + O_AGGH + (size_t)row * 64;
        #pragma unroll
        for (int j = 0; j < 64; ++j) unsafeAtomicAdd(&ah[j], acc[j]);
    }

    // edge_feat -> LDS for coord MLP
    #pragma unroll
    for (int j = 0; j < 64; ++j) my[j] = acc[j];

    // coord MLP hidden
    #pragma unroll
    for (int j = 0; j < 64; ++j) acc[j] = wf[O_BC1 + j];
    for (int k = 0; k < 64; ++k) {
        float a = my[k];
        const float* w = wf + O_WC1 + k * 64;
        #pragma unroll
        for (int j = 0; j < 64; ++j) acc[j] = fmaf(a, w[j], acc[j]);
    }
    // gate = relu(hidden) . Wc2 + bc2
    float gate = wf[O_BC2];
    #pragma unroll
    for (int k = 0; k < 64; ++k) gate = fmaf(fmaxf(acc[k], 0.0f), wf[O_WC2 + k], gate);

    float tx = fminf(fmaxf(cdx * gate, -100.0f), 100.0f);
    float ty = fminf(fmaxf(cdy * gate, -100.0f), 100.0f);
    float tz = fminf(fmaxf(cdz * gate, -100.0f), 100.0f);
    unsafeAtomicAdd(&ws[O_SUMT + 3*row + 0], tx);
    unsafeAtomicAdd(&ws[O_SUMT + 3*row + 1], ty);
    unsafeAtomicAdd(&ws[O_SUMT + 3*row + 2], tz);
    unsafeAtomicAdd(&ws[O_CNT + row], 1.0f);
}

__global__ __launch_bounds__(128) void edge_kernel(
    const void* __restrict__ h, const void* __restrict__ coord,
    const int* __restrict__ ei, float* __restrict__ ws)
{
    __shared__ float sbuf[128 * 65];          // 65-pad: bank (65t+k)%32 conflict-free
    int e = blockIdx.x * 128 + threadIdx.x;
    if (e >= NE) return;
    float* my = &sbuf[threadIdx.x * 65];
    if (((const int*)ws)[O_FLAG])
        edge_core<true>(h, coord, ei, ws, e, my);
    else
        edge_core<false>(h, coord, ei, ws, e, my);
}

// ---- per-node core: coord/vel update + node MLP + residual ----
template<bool B16>
static __device__ __forceinline__ void node_core(
    const void* __restrict__ h, const void* __restrict__ coord,
    const void* __restrict__ vel, const float* __restrict__ ws,
    void* __restrict__ out, int n, float* my)
{
    float c = ws[O_CNT + n];
    float inv = (c > 0.0f) ? (1.0f / fmaxf(c, 1.0f)) : 0.0f;
    #pragma unroll
    for (int i = 0; i < 3; ++i) {
        float aggc = ws[O_SUMT + 3*n + i] * inv;            // COORDS_WEIGHT = 1
        float v = ldf<B16>(vel, 3*n + i) + aggc * 0.125f;   // inv_L = 1/8
        float cn = ldf<B16>(coord, 3*n + i) + v * 0.125f;
        stf<B16>(out, OUT_COORD + 3*n + i, cn);
        stf<B16>(out, OUT_V + 3*n + i, v);
    }

    float acc[64];
    #pragma unroll
    for (int j = 0; j < 64; ++j) acc[j] = ws[O_BN1 + j];

    // node MLP layer 1: k = 0..63 (h[n])
    for (int k = 0; k < 64; ++k) {
        float a = ldf<B16>(h, (size_t)n * 64 + k);
        const float* w = ws + O_WN1 + k * 64;
        #pragma unroll
        for (int j = 0; j < 64; ++j) acc[j] = fmaf(a, w[j], acc[j]);
    }
    // k = 64..127 (agg_h[n], fp32)
    const float* ag = ws + O_AGGH + (size_t)n * 64;
    for (int k = 0; k < 64; ++k) {
        float a = ag[k];
        const float* w = ws + O_WN1 + (64 + k) * 64;
        #pragma unroll
        for (int j = 0; j < 64; ++j) acc[j] = fmaf(a, w[j], acc[j]);
    }

    #pragma unroll
    for (int j = 0; j < 64; ++j) my[j] = fmaxf(acc[j], 0.0f);

    // layer 2
    #pragma unroll
    for (int j = 0; j < 64; ++j) acc[j] = ws[O_BN2 + j];
    for (int k = 0; k < 64; ++k) {
        float a = my[k];
        const float* w = ws + O_WN2 + k * 64;
        #pragma unroll
        for (int j = 0; j < 64; ++j) acc[j] = fmaf(a, w[j], acc[j]);
    }

    // residual + store (out dtype == input dtype)
    #pragma unroll
    for (int j = 0; j < 64; ++j) {
        float ho = ldf<B16>(h, (size_t)n * 64 + j) + acc[j];
        stf<B16>(out, (size_t)n * 64 + j, ho);
    }
}

__global__ __launch_bounds__(128) void node_kernel(
    const void* __restrict__ h, const void* __restrict__ coord,
    const void* __restrict__ vel, const float* __restrict__ ws,
    void* __restrict__ out)
{
    __shared__ float sbuf[128 * 65];
    int n = blockIdx.x * 128 + threadIdx.x;
    if (n >= NN) return;
    float* my = &sbuf[threadIdx.x * 65];
    if (((const int*)ws)[O_FLAG])
        node_core<true>(h, coord, vel, ws, out, n, my);
    else
        node_core<false>(h, coord, vel, ws, out, n, my);
}

extern "C" void kernel_launch(void* const* d_in, const int* in_sizes, int n_in,
                              void* d_out, int out_size, void* d_ws, size_t ws_size,
                              hipStream_t stream) {
    const void* h     = d_in[0];
    const void* coord = d_in[1];
    const void* vel   = d_in[2];
    // d_in[3] = vel_init (unused by reference)
    const int* eidx = (const int*)d_in[4];

    float* ws = (float*)d_ws;

    // decide tensor dtype (writes O_FLAG)
    sniff_kernel<<<1, 1, 0, stream>>>((const uint32_t*)d_in[5], ws);

    // zero the scatter-accumulation region (ws is poisoned 0xAA before every call)
    hipMemsetAsync((char*)d_ws + (size_t)O_AGGH * sizeof(float), 0,
                   (size_t)(WS_FLOATS - O_AGGH) * sizeof(float), stream);

    prep_kernel<<<64, 256, 0, stream>>>(d_in[5], d_in[6], d_in[7], d_in[8],
                                        d_in[9], d_in[10], d_in[11], d_in[12],
                                        d_in[13], d_in[14], d_in[15], d_in[16], ws);

    edge_kernel<<<NE / 128, 128, 0, stream>>>(h, coord, eidx, ws);

    node_kernel<<<(NN + 127) / 128, 128, 0, stream>>>(h, coord, vel, ws, d_out);
}

// Round 4
// 1263.921 us; speedup vs baseline: 2.7439x; 2.7439x over previous
//
#include <hip/hip_runtime.h>
#include <hip/hip_bf16.h>
#include <stdint.h>

#define NE 800000
#define NN 50000

// ---- shared weight region (float offsets, both paths) ----
#define O_W1   0          // We1  [129*64]
#define O_B1   8256       // be1  [64]
#define O_W2   8320       // We2  [64*64]
#define O_B2   12416      // be2  [64]
#define O_WC1  12480      // Wc1  [64*64]
#define O_BC1  16576      // bc1  [64]
#define O_WC2  16640      // Wc2  [64]
#define O_BC2  16704      // bc2  [1]
#define O_WN1  16768      // Wn1  [128*64]
#define O_BN1  24960      // bn1  [64]
#define O_WN2  25024      // Wn2  [64*64]
#define O_BN2  29120      // bn2  [64]
#define O_FLAG 29184      // int: 1 = tensors are bf16, 0 = f32

// ---- OLD (atomic fallback) layout ----
#define F_AGGH 29248
#define F_SUMT (F_AGGH + NN*64)
#define F_CNT  (F_SUMT + NN*3)
#define F_TOTAL (F_CNT + NN)

// ---- NEW (CSR) layout ----
#define N_OFF   29248               // int off[NN+1]
#define N_CUR   (N_OFF + 50008)     // int cur[NN] (counts, then cursors)
#define N_ELIST (N_CUR + NN)        // int elist[NE]
#define N_AGGH  (N_ELIST + NE)      // float [NN*64]
#define N_SUMT  (N_AGGH + NN*64)    // float [NN*3]
#define N_EF    (N_SUMT + NN*3)     // float [NE*64]  (16B aligned: 4279256%4==0)
#define N_TR    (N_EF + NE*64)      // float [NE*3]
#define N_TOTAL (N_TR + NE*3)       // 57,879,256 floats = 231.5 MB

#define OUT_COORD (NN*64)
#define OUT_V     (NN*64 + NN*3)

static __device__ __forceinline__ float bf2f(const __hip_bfloat16 x) { return __bfloat162float(x); }

template<bool B16>
static __device__ __forceinline__ float ldf(const void* p, size_t i) {
    if (B16) return __bfloat162float(((const __hip_bfloat16*)p)[i]);
    else     return ((const float*)p)[i];
}
template<bool B16>
static __device__ __forceinline__ void stf(void* p, size_t i, float v) {
    if (B16) ((__hip_bfloat16*)p)[i] = __float2bfloat16(v);
    else     ((float*)p)[i] = v;
}

// ---- dtype sniff (see R2 notes): P(wrong) ~ 0.48^128 ----
__global__ void sniff_kernel(const uint32_t* __restrict__ w, float* __restrict__ ws) {
    int bad = 0;
    for (int i = 0; i < 128; ++i) {
        uint32_t d = w[i];
        float a = __uint_as_float(d << 16);
        float b = __uint_as_float(d & 0xffff0000u);
        if (!(fabsf(a) <= 0.1f)) bad++;
        if (!(fabsf(b) <= 0.1f)) bad++;
    }
    ((int*)ws)[O_FLAG] = (bad == 0) ? 1 : 0;
}

// ---- weights -> fp32 in ws ----
__global__ void prep_kernel(
    const void* We1, const void* be1, const void* We2, const void* be2,
    const void* Wn1, const void* bn1, const void* Wn2, const void* bn2,
    const void* Wc1, const void* bc1, const void* Wc2, const void* bc2,
    float* __restrict__ wf)
{
    const int isb = ((const int*)wf)[O_FLAG];
    int tid = blockIdx.x * blockDim.x + threadIdx.x;
    int stride = gridDim.x * blockDim.x;
#define CP(dst, src, n) \
    for (int i = tid; i < (n); i += stride) \
        wf[(dst) + i] = isb ? bf2f(((const __hip_bfloat16*)(src))[i]) \
                            : ((const float*)(src))[i];
    CP(O_W1,  We1, 129*64)  CP(O_B1,  be1, 64)
    CP(O_W2,  We2, 64*64)   CP(O_B2,  be2, 64)
    CP(O_WC1, Wc1, 64*64)   CP(O_BC1, bc1, 64)
    CP(O_WC2, Wc2, 64)      CP(O_BC2, bc2, 1)
    CP(O_WN1, Wn1, 128*64)  CP(O_BN1, bn1, 64)
    CP(O_WN2, Wn2, 64*64)   CP(O_BN2, bn2, 64)
#undef CP
}

// ---- edge MLP core: fills acc[64]=edge_feat(post-relu), gate, coord diff ----
template<bool B16>
static __device__ __forceinline__ void edge_mlp(
    const void* __restrict__ h, const void* __restrict__ coord,
    const float* __restrict__ wf, int row, int col, float* my,
    float acc[64], float& gate, float& cdx, float& cdy, float& cdz)
{
    cdx = ldf<B16>(coord, 3*row + 0) - ldf<B16>(coord, 3*col + 0);
    cdy = ldf<B16>(coord, 3*row + 1) - ldf<B16>(coord, 3*col + 1);
    cdz = ldf<B16>(coord, 3*row + 2) - ldf<B16>(coord, 3*col + 2);
    float radial = cdx*cdx + cdy*cdy + cdz*cdz;

    #pragma unroll
    for (int j = 0; j < 64; ++j) acc[j] = wf[O_B1 + j];
    for (int k = 0; k < 64; ++k) {
        float a = ldf<B16>(h, (size_t)row * 64 + k);
        const float* w = wf + O_W1 + k * 64;
        #pragma unroll
        for (int j = 0; j < 64; ++j) acc[j] = fmaf(a, w[j], acc[j]);
    }
    for (int k = 0; k < 64; ++k) {
        float a = ldf<B16>(h, (size_t)col * 64 + k);
        const float* w = wf + O_W1 + (64 + k) * 64;
        #pragma unroll
        for (int j = 0; j < 64; ++j) acc[j] = fmaf(a, w[j], acc[j]);
    }
    {
        const float* w = wf + O_W1 + 128 * 64;
        #pragma unroll
        for (int j = 0; j < 64; ++j) acc[j] = fmaf(radial, w[j], acc[j]);
    }
    #pragma unroll
    for (int j = 0; j < 64; ++j) my[j] = fmaxf(acc[j], 0.0f);

    #pragma unroll
    for (int j = 0; j < 64; ++j) acc[j] = wf[O_B2 + j];
    for (int k = 0; k < 64; ++k) {
        float a = my[k];
        const float* w = wf + O_W2 + k * 64;
        #pragma unroll
        for (int j = 0; j < 64; ++j) acc[j] = fmaf(a, w[j], acc[j]);
    }
    #pragma unroll
    for (int j = 0; j < 64; ++j) acc[j] = fmaxf(acc[j], 0.0f);   // edge_feat

    #pragma unroll
    for (int j = 0; j < 64; ++j) my[j] = acc[j];

    float hid[64];
    #pragma unroll
    for (int j = 0; j < 64; ++j) hid[j] = wf[O_BC1 + j];
    for (int k = 0; k < 64; ++k) {
        float a = my[k];
        const float* w = wf + O_WC1 + k * 64;
        #pragma unroll
        for (int j = 0; j < 64; ++j) hid[j] = fmaf(a, w[j], hid[j]);
    }
    gate = wf[O_BC2];
    #pragma unroll
    for (int k = 0; k < 64; ++k) gate = fmaf(fmaxf(hid[k], 0.0f), wf[O_WC2 + k], gate);
}

// ============ NEW PATH: store + CSR + gather ============
template<bool B16>
static __device__ __forceinline__ void edge_store_core(
    const void* __restrict__ h, const void* __restrict__ coord,
    const int* __restrict__ ei, float* __restrict__ ws, int e, float* my)
{
    int row = ei[e];
    int col = ei[NE + e];
    float acc[64], gate, cdx, cdy, cdz;
    edge_mlp<B16>(h, coord, ws, row, col, my, acc, gate, cdx, cdy, cdz);

    // store edge_feat (float4) and trans; histogram row counts
    float4* efv = (float4*)(ws + N_EF + (size_t)e * 64);
    #pragma unroll
    for (int q = 0; q < 16; ++q)
        efv[q] = make_float4(acc[4*q], acc[4*q+1], acc[4*q+2], acc[4*q+3]);

    ws[N_TR + 3*e + 0] = fminf(fmaxf(cdx * gate, -100.0f), 100.0f);
    ws[N_TR + 3*e + 1] = fminf(fmaxf(cdy * gate, -100.0f), 100.0f);
    ws[N_TR + 3*e + 2] = fminf(fmaxf(cdz * gate, -100.0f), 100.0f);

    atomicAdd((int*)ws + N_CUR + row, 1);
}

__global__ __launch_bounds__(128) void edge_store_kernel(
    const void* __restrict__ h, const void* __restrict__ coord,
    const int* __restrict__ ei, float* __restrict__ ws)
{
    __shared__ float sbuf[128 * 65];
    int e = blockIdx.x * 128 + threadIdx.x;
    if (e >= NE) return;
    float* my = &sbuf[threadIdx.x * 65];
    if (((const int*)ws)[O_FLAG]) edge_store_core<true>(h, coord, ei, ws, e, my);
    else                          edge_store_core<false>(h, coord, ei, ws, e, my);
}

// single-block exclusive scan of counts (in N_CUR) -> N_OFF; reset cursors
__global__ __launch_bounds__(1024) void scan_kernel(float* __restrict__ ws) {
    int* cnt = (int*)ws + N_CUR;
    int* off = (int*)ws + N_OFF;
    __shared__ int tmp[1024];
    __shared__ int carry_s;
    int tid = threadIdx.x;
    if (tid == 0) carry_s = 0;
    __syncthreads();
    for (int base = 0; base < NN; base += 1024) {
        int i = base + tid;
        int v = (i < NN) ? cnt[i] : 0;
        tmp[tid] = v;
        __syncthreads();
        #pragma unroll
        for (int s = 1; s < 1024; s <<= 1) {
            int t = (tid >= s) ? tmp[tid - s] : 0;
            __syncthreads();
            tmp[tid] += t;
            __syncthreads();
        }
        int incl = tmp[tid];
        int excl = carry_s + incl - v;
        if (i < NN) { off[i] = excl; cnt[i] = excl; }   // cnt[] becomes cursor[]
        __syncthreads();
        if (tid == 1023) carry_s += incl;
        __syncthreads();
    }
    if (tid == 0) off[NN] = carry_s;
}

__global__ __launch_bounds__(256) void scatter_kernel(
    const int* __restrict__ ei, float* __restrict__ ws)
{
    int e = blockIdx.x * 256 + threadIdx.x;
    if (e >= NE) return;
    int row = ei[e];
    int pos = atomicAdd((int*)ws + N_CUR + row, 1);
    ((int*)ws)[N_ELIST + pos] = e;
}

// one wave per node: lane j sums feature j over the node's edge list
__global__ __launch_bounds__(256) void agg_kernel(float* __restrict__ ws) {
    int node = (blockIdx.x * 256 + threadIdx.x) >> 6;
    int lane = threadIdx.x & 63;
    if (node >= NN) return;
    const int* off = (const int*)ws + N_OFF;
    const int* elist = (const int*)ws + N_ELIST;
    const float* ef = ws + N_EF;
    const float* tr = ws + N_TR;
    int s = off[node], t = off[node + 1];
    float sum = 0.0f, ts = 0.0f;
    for (int i = s; i < t; ++i) {
        int ed = elist[i];
        sum += ef[(size_t)ed * 64 + lane];
        if (lane < 3) ts += tr[3*ed + lane];
    }
    ws[N_AGGH + (size_t)node * 64 + lane] = sum;
    if (lane < 3) ws[N_SUMT + 3*node + lane] = ts;
}

// ---- node MLP core (shared by both paths) ----
template<bool B16>
static __device__ __forceinline__ void node_core(
    const void* __restrict__ h, const void* __restrict__ coord,
    const void* __restrict__ vel, const float* __restrict__ ws,
    const float* __restrict__ agg, const float* __restrict__ sumt, float cntf,
    void* __restrict__ out, int n, float* my)
{
    float inv = (cntf > 0.0f) ? (1.0f / fmaxf(cntf, 1.0f)) : 0.0f;
    #pragma unroll
    for (int i = 0; i < 3; ++i) {
        float aggc = sumt[3*n + i] * inv;
        float v = ldf<B16>(vel, 3*n + i) + aggc * 0.125f;
        float cn = ldf<B16>(coord, 3*n + i) + v * 0.125f;
        stf<B16>(out, OUT_COORD + 3*n + i, cn);
        stf<B16>(out, OUT_V + 3*n + i, v);
    }

    float acc[64];
    #pragma unroll
    for (int j = 0; j < 64; ++j) acc[j] = ws[O_BN1 + j];
    for (int k = 0; k < 64; ++k) {
        float a = ldf<B16>(h, (size_t)n * 64 + k);
        const float* w = ws + O_WN1 + k * 64;
        #pragma unroll
        for (int j = 0; j < 64; ++j) acc[j] = fmaf(a, w[j], acc[j]);
    }
    const float* ag = agg + (size_t)n * 64;
    for (int k = 0; k < 64; ++k) {
        float a = ag[k];
        const float* w = ws + O_WN1 + (64 + k) * 64;
        #pragma unroll
        for (int j = 0; j < 64; ++j) acc[j] = fmaf(a, w[j], acc[j]);
    }
    #pragma unroll
    for (int j = 0; j < 64; ++j) my[j] = fmaxf(acc[j], 0.0f);
    #pragma unroll
    for (int j = 0; j < 64; ++j) acc[j] = ws[O_BN2 + j];
    for (int k = 0; k < 64; ++k) {
        float a = my[k];
        const float* w = ws + O_WN2 + k * 64;
        #pragma unroll
        for (int j = 0; j < 64; ++j) acc[j] = fmaf(a, w[j], acc[j]);
    }
    #pragma unroll
    for (int j = 0; j < 64; ++j) {
        float ho = ldf<B16>(h, (size_t)n * 64 + j) + acc[j];
        stf<B16>(out, (size_t)n * 64 + j, ho);
    }
}

__global__ __launch_bounds__(128) void node_kernel_csr(
    const void* __restrict__ h, const void* __restrict__ coord,
    const void* __restrict__ vel, const float* __restrict__ ws,
    void* __restrict__ out)
{
    __shared__ float sbuf[128 * 65];
    int n = blockIdx.x * 128 + threadIdx.x;
    if (n >= NN) return;
    float* my = &sbuf[threadIdx.x * 65];
    const int* off = (const int*)ws + N_OFF;
    float cntf = (float)(off[n + 1] - off[n]);
    if (((const int*)ws)[O_FLAG])
        node_core<true>(h, coord, vel, ws, ws + N_AGGH, ws + N_SUMT, cntf, out, n, my);
    else
        node_core<false>(h, coord, vel, ws, ws + N_AGGH, ws + N_SUMT, cntf, out, n, my);
}

// ============ FALLBACK PATH (round-3 atomics) ============
template<bool B16>
static __device__ __forceinline__ void edge_atomic_core(
    const void* __restrict__ h, const void* __restrict__ coord,
    const int* __restrict__ ei, float* __restrict__ ws, int e, float* my)
{
    int row = ei[e];
    int col = ei[NE + e];
    float acc[64], gate, cdx, cdy, cdz;
    edge_mlp<B16>(h, coord, ws, row, col, my, acc, gate, cdx, cdy, cdz);

    float* ah = ws + F_AGGH + (size_t)row * 64;
    #pragma unroll
    for (int j = 0; j < 64; ++j) unsafeAtomicAdd(&ah[j], acc[j]);
    unsafeAtomicAdd(&ws[F_SUMT + 3*row + 0], fminf(fmaxf(cdx * gate, -100.0f), 100.0f));
    unsafeAtomicAdd(&ws[F_SUMT + 3*row + 1], fminf(fmaxf(cdy * gate, -100.0f), 100.0f));
    unsafeAtomicAdd(&ws[F_SUMT + 3*row + 2], fminf(fmaxf(cdz * gate, -100.0f), 100.0f));
    unsafeAtomicAdd(&ws[F_CNT + row], 1.0f);
}

__global__ __launch_bounds__(128) void edge_atomic_kernel(
    const void* __restrict__ h, const void* __restrict__ coord,
    const int* __restrict__ ei, float* __restrict__ ws)
{
    __shared__ float sbuf[128 * 65];
    int e = blockIdx.x * 128 + threadIdx.x;
    if (e >= NE) return;
    float* my = &sbuf[threadIdx.x * 65];
    if (((const int*)ws)[O_FLAG]) edge_atomic_core<true>(h, coord, ei, ws, e, my);
    else                          edge_atomic_core<false>(h, coord, ei, ws, e, my);
}

__global__ __launch_bounds__(128) void node_kernel_atomic(
    const void* __restrict__ h, const void* __restrict__ coord,
    const void* __restrict__ vel, const float* __restrict__ ws,
    void* __restrict__ out)
{
    __shared__ float sbuf[128 * 65];
    int n = blockIdx.x * 128 + threadIdx.x;
    if (n >= NN) return;
    float* my = &sbuf[threadIdx.x * 65];
    float cntf = ws[F_CNT + n];
    if (((const int*)ws)[O_FLAG])
        node_core<true>(h, coord, vel, ws, ws + F_AGGH, ws + F_SUMT, cntf, out, n, my);
    else
        node_core<false>(h, coord, vel, ws, ws + F_AGGH, ws + F_SUMT, cntf, out, n, my);
}

extern "C" void kernel_launch(void* const* d_in, const int* in_sizes, int n_in,
                              void* d_out, int out_size, void* d_ws, size_t ws_size,
                              hipStream_t stream) {
    const void* h     = d_in[0];
    const void* coord = d_in[1];
    const void* vel   = d_in[2];
    const int* eidx = (const int*)d_in[4];
    float* ws = (float*)d_ws;

    sniff_kernel<<<1, 1, 0, stream>>>((const uint32_t*)d_in[5], ws);
    prep_kernel<<<64, 256, 0, stream>>>(d_in[5], d_in[6], d_in[7], d_in[8],
                                        d_in[9], d_in[10], d_in[11], d_in[12],
                                        d_in[13], d_in[14], d_in[15], d_in[16], ws);

    const bool big = ws_size >= (size_t)N_TOTAL * sizeof(float);
    if (big) {
        // zero histogram counters only
        hipMemsetAsync((char*)d_ws + (size_t)N_CUR * 4, 0, (size_t)NN * 4, stream);
        edge_store_kernel<<<NE / 128, 128, 0, stream>>>(h, coord, eidx, ws);
        scan_kernel<<<1, 1024, 0, stream>>>(ws);
        scatter_kernel<<<(NE + 255) / 256, 256, 0, stream>>>(eidx, ws);
        agg_kernel<<<(NN * 64 + 255) / 256, 256, 0, stream>>>(ws);
        node_kernel_csr<<<(NN + 127) / 128, 128, 0, stream>>>(h, coord, vel, ws, d_out);
    } else {
        hipMemsetAsync((char*)d_ws + (size_t)F_AGGH * 4, 0,
                       (size_t)(F_TOTAL - F_AGGH) * 4, stream);
        edge_atomic_kernel<<<NE / 128, 128, 0, stream>>>(h, coord, eidx, ws);
        node_kernel_atomic<<<(NN + 127) / 128, 128, 0, stream>>>(h, coord, vel, ws, d_out);
    }
}